// Round 1
// baseline (213.229 us; speedup 1.0000x reference)
//
#include <hip/hip_runtime.h>
#include <cmath>

#define N_NODES 30460
#define D 64
#define B 128
#define K_SEL 6924
#define S_TOT (B * K_SEL)      /* 886272 */
#define NPADH 30464            /* 952*32 ; pad rows hold abstract row */
#define CVT_BLOCKS 952         /* 32 rows per block */

/* ws layout (float offsets): Q [2*B*D] | Gh (half) [NPADH*D] */
#define WS_Q 0
#define WS_GH (2 * B * D)      /* 16384 floats = 64 KB, aligned */

typedef _Float16 half_t;
typedef _Float16 half8 __attribute__((ext_vector_type(8)));

/* ---- prep: blocks [0,952) convert graph rows to fp16; blocks [952,984)
   compute portrait + tw + Q = tw*utter + (1-tw)*port per (layer,batch) ---- */
__global__ __launch_bounds__(256) void k_prep(
    const float* __restrict__ graph, const float* __restrict__ abs_e,
    const float* __restrict__ utter,
    const float* __restrict__ Wa, const float* __restrict__ Va,
    const float* __restrict__ W1w, const float* __restrict__ W1b,
    const float* __restrict__ W2w, const float* __restrict__ W2b,
    const int* __restrict__ midx,
    const int* __restrict__ la0, const int* __restrict__ it0,
    const int* __restrict__ la1, const int* __restrict__ it1,
    float* __restrict__ ws) {
    const int blk = blockIdx.x, t = threadIdx.x;

    if (blk < CVT_BLOCKS) {
        /* 32 rows/block, 8 lanes/row, 8 floats/lane -> half8 stores (128B/row) */
        int r = blk * 32 + (t >> 3), c = t & 7;
        const float* src = (r < N_NODES) ? (graph + (size_t)r * D) : abs_e;
        float4 a = *(const float4*)(src + c * 8);
        float4 b = *(const float4*)(src + c * 8 + 4);
        half8 h;
        h[0] = (half_t)a.x; h[1] = (half_t)a.y; h[2] = (half_t)a.z; h[3] = (half_t)a.w;
        h[4] = (half_t)b.x; h[5] = (half_t)b.y; h[6] = (half_t)b.z; h[7] = (half_t)b.w;
        half_t* Gh = (half_t*)(ws + WS_GH);
        *(half8*)(Gh + (size_t)r * D + c * 8) = h;
        return;
    }

    /* ---- portrait + Q: one wave per batch ---- */
    __shared__ float sExp[4][64];
    __shared__ int   sIdx[4][64];
    int wave = t >> 6, lane = t & 63;
    int g = (blk - CVT_BLOCKS) * 4 + wave;           /* batch 0..127 */

    float e = 0.f; int mi = 0;
    if (lane < 50) {
        mi = midx[g * 50 + lane];
        const float* me = graph + (size_t)mi * D;
        float h[20];
#pragma unroll
        for (int j = 0; j < 20; j++) h[j] = 0.f;
#pragma unroll
        for (int d4 = 0; d4 < 16; ++d4) {
            float4 v = *(const float4*)(me + d4 * 4);
#pragma unroll
            for (int j = 0; j < 20; j++)
                h[j] += v.x * Wa[(d4 * 4 + 0) * 20 + j]
                      + v.y * Wa[(d4 * 4 + 1) * 20 + j]
                      + v.z * Wa[(d4 * 4 + 2) * 20 + j]
                      + v.w * Wa[(d4 * 4 + 3) * 20 + j];
        }
        float beta = 0.f;
#pragma unroll
        for (int j = 0; j < 20; j++) beta += tanhf(h[j]) * Va[j];
        e = expf(beta);
    }
    sExp[wave][lane] = e;
    sIdx[wave][lane] = mi;
    __syncthreads();

    float x = e;
    x += __shfl_xor(x, 32, 64); x += __shfl_xor(x, 16, 64);
    x += __shfl_xor(x, 8, 64);  x += __shfl_xor(x, 4, 64);
    x += __shfl_xor(x, 2, 64);  x += __shfl_xor(x, 1, 64);

    float acc = 0.f;
#pragma unroll 5
    for (int m = 0; m < 50; m++)
        acc += sExp[wave][m] * graph[(size_t)sIdx[wave][m] * D + lane];
    float p = acc / x;                                /* portrait[g][lane] */
    float u = utter[(size_t)g * D + lane];

#pragma unroll
    for (int l = 0; l < 2; ++l) {
        const int* lap = l ? la1 : la0;
        const int* itp = l ? it1 : it0;
        const float* Ww = l ? W2w : W1w;
        const float* Wb = l ? W2b : W1b;
        int li = lap[g], it = itp[g];
        const float* wr = Ww + it * 3 * D;
        float sv = (li < N_NODES) ? graph[(size_t)li * D + lane] : abs_e[lane];
        float a = wr[lane] * u + wr[D + lane] * p + wr[2 * D + lane] * sv;
        a += __shfl_xor(a, 32, 64); a += __shfl_xor(a, 16, 64);
        a += __shfl_xor(a, 8, 64);  a += __shfl_xor(a, 4, 64);
        a += __shfl_xor(a, 2, 64);  a += __shfl_xor(a, 1, 64);
        float tw = 1.f / (1.f + expf(-(a + Wb[it])));
        ws[WS_Q + ((size_t)l * B + g) * D + lane] = tw * u + (1.f - tw) * p;
    }
}

/* ---- scoring: out[l][s] = Q[l][bat] . Gh[si[s]]
   8 lanes per output, each lane one half8 chunk (full 128B row = 2 lines,
   16 cache-line transactions per wave gather instr) ---- */
__global__ __launch_bounds__(256) void k_score(
    const int* __restrict__ si0, const int* __restrict__ si1,
    const float* __restrict__ ws, float* __restrict__ out) {
    __shared__ float sOut[256];
    const int t = threadIdx.x;
    const int l = blockIdx.y;
    const int s0 = blockIdx.x * 256;
    const int* __restrict__ si = l ? si1 : si0;
    const half_t* __restrict__ Gh = (const half_t*)(ws + WS_GH);
    const float* __restrict__ Qf = ws + WS_Q + (size_t)l * B * D;
    const int grp = t >> 3, c = t & 7;

#pragma unroll
    for (int pass = 0; pass < 8; ++pass) {
        int o = pass * 32 + grp;
        int s = s0 + o;
        int idx = si[s];
        unsigned bat = (unsigned)s / (unsigned)K_SEL;
        half8 gv = *(const half8*)(Gh + (size_t)idx * D + c * 8);
        const float* q = Qf + (size_t)bat * D + c * 8;
        float4 qa = *(const float4*)(q);
        float4 qb = *(const float4*)(q + 4);
        float acc = (float)gv[0] * qa.x + (float)gv[1] * qa.y
                  + (float)gv[2] * qa.z + (float)gv[3] * qa.w
                  + (float)gv[4] * qb.x + (float)gv[5] * qb.y
                  + (float)gv[6] * qb.z + (float)gv[7] * qb.w;
        acc += __shfl_xor(acc, 4, 64);
        acc += __shfl_xor(acc, 2, 64);
        acc += __shfl_xor(acc, 1, 64);
        if (c == 0) sOut[o] = acc;
    }
    __syncthreads();
    __builtin_nontemporal_store(sOut[t], &out[(size_t)l * S_TOT + s0 + t]);
}

extern "C" void kernel_launch(void* const* d_in, const int* in_sizes, int n_in,
                              void* d_out, int out_size, void* d_ws, size_t ws_size,
                              hipStream_t stream) {
    const float* graph = (const float*)d_in[0];
    const float* utter = (const float*)d_in[1];
    const float* abs_e = (const float*)d_in[2];
    const float* Wa    = (const float*)d_in[3];
    const float* Va    = (const float*)d_in[4];
    const float* W1w   = (const float*)d_in[5];
    const float* W1b   = (const float*)d_in[6];
    const float* W2w   = (const float*)d_in[7];
    const float* W2b   = (const float*)d_in[8];
    const int* midx = (const int*)d_in[9];
    const int* si0 = (const int*)d_in[11];
    const int* la0 = (const int*)d_in[15];
    const int* it0 = (const int*)d_in[16];
    const int* si1 = (const int*)d_in[17];
    const int* la1 = (const int*)d_in[21];
    const int* it1 = (const int*)d_in[22];

    float* ws = (float*)d_ws;

    k_prep<<<CVT_BLOCKS + 32, 256, 0, stream>>>(graph, abs_e, utter, Wa, Va,
                                                W1w, W1b, W2w, W2b, midx,
                                                la0, it0, la1, it1, ws);

    dim3 grid(S_TOT / 256, 2);   /* 3462 x 2 */
    k_score<<<grid, 256, 0, stream>>>(si0, si1, ws, (float*)d_out);
}

// Round 4
// 156.772 us; speedup vs baseline: 1.3601x; 1.3601x over previous
//
#include <hip/hip_runtime.h>
#include <cmath>

#define N_NODES 30460
#define D 64
#define B 128
#define K_SEL 6924
#define S_TOT (B * K_SEL)      /* 886272 */
#define NPAD 30464             /* 238*128 ; rows >= N_NODES hold abstract row */
#define NB_CHUNKS 238

/* ws layout (float offsets): port [B*D] | tw [2*B] | tab float2 [B*NPAD] (~31.2 MB) */
#define WS_PORT 0
#define WS_TW   (B * D)
#define WS_TAB  (B * D + 2 * B)

typedef _Float16 half_t;
typedef _Float16 half8 __attribute__((ext_vector_type(8)));
typedef float f32x4 __attribute__((ext_vector_type(4)));
typedef float f32x2 __attribute__((ext_vector_type(2)));

#define STRG 136   /* Gs stride in halves: 64 hi | 64 lo | 8 pad ; 272 B, 16-aligned */
#define STRX 72    /* Xs stride in halves: 64 + 8 pad ; 144 B, 16-aligned */

/* ---- portrait + tw: 4 waves/block x 32 blocks = 128 batches (proven structure) ---- */
__global__ __launch_bounds__(256) void k_port(
    const float* __restrict__ graph, const float* __restrict__ abs_e,
    const float* __restrict__ utter,
    const float* __restrict__ Wa, const float* __restrict__ Va,
    const float* __restrict__ W1w, const float* __restrict__ W1b,
    const float* __restrict__ W2w, const float* __restrict__ W2b,
    const int* __restrict__ midx,
    const int* __restrict__ la0, const int* __restrict__ it0,
    const int* __restrict__ la1, const int* __restrict__ it1,
    float* __restrict__ ws) {
    __shared__ float sWa[D * 24];     /* padded stride 24 -> 16B-aligned float4 rows */
    __shared__ float sVa[20];
    __shared__ float sExp[4][64];
    __shared__ int   sIdx[4][64];
    int t = threadIdx.x, wave = t >> 6, lane = t & 63;
    for (int i = t; i < D * 20; i += 256) {
        int d = i / 20, j = i - d * 20;
        sWa[d * 24 + j] = Wa[i];
    }
    if (t < 20) sVa[t] = Va[t];
    __syncthreads();

    int b = blockIdx.x * 4 + wave;
    float e = 0.f; int mi = 0;
    if (lane < 50) {
        mi = midx[b * 50 + lane];
        const float* me = graph + (size_t)mi * D;
        float h[20];
#pragma unroll
        for (int j = 0; j < 20; j++) h[j] = 0.f;
#pragma unroll 2
        for (int d4 = 0; d4 < 16; ++d4) {
            float4 v = *(const float4*)(me + d4 * 4);
            const float* wb = &sWa[(d4 * 4) * 24];
#pragma unroll
            for (int e2 = 0; e2 < 4; ++e2) {
                float vv = (e2 == 0) ? v.x : (e2 == 1) ? v.y : (e2 == 2) ? v.z : v.w;
                const float* wr = wb + e2 * 24;
#pragma unroll
                for (int j4 = 0; j4 < 5; ++j4) {
                    float4 w = *(const float4*)(wr + j4 * 4);
                    h[j4 * 4 + 0] += vv * w.x;
                    h[j4 * 4 + 1] += vv * w.y;
                    h[j4 * 4 + 2] += vv * w.z;
                    h[j4 * 4 + 3] += vv * w.w;
                }
            }
        }
        float beta = 0.f;
#pragma unroll
        for (int j = 0; j < 20; j++) beta += tanhf(h[j]) * sVa[j];
        e = expf(beta);
    }
    sExp[wave][lane] = e;
    sIdx[wave][lane] = mi;
    __syncthreads();

    float x = e;
    x += __shfl_xor(x, 32, 64); x += __shfl_xor(x, 16, 64);
    x += __shfl_xor(x, 8, 64);  x += __shfl_xor(x, 4, 64);
    x += __shfl_xor(x, 2, 64);  x += __shfl_xor(x, 1, 64);

    float acc = 0.f;
#pragma unroll 5
    for (int m = 0; m < 50; m++)
        acc += sExp[wave][m] * graph[(size_t)sIdx[wave][m] * D + lane];
    float p = acc / x;
    ws[WS_PORT + b * D + lane] = p;
    float u = utter[(size_t)b * D + lane];

#pragma unroll
    for (int l = 0; l < 2; ++l) {
        const int* lap = l ? la1 : la0;
        const int* itp = l ? it1 : it0;
        const float* Ww = l ? W2w : W1w;
        const float* Wb = l ? W2b : W1b;
        int li = lap[b], it = itp[b];
        const float* wr = Ww + it * 3 * D;
        float sv = (li < N_NODES) ? graph[(size_t)li * D + lane] : abs_e[lane];
        float a = wr[lane] * u + wr[D + lane] * p + wr[2 * D + lane] * sv;
        a += __shfl_xor(a, 32, 64); a += __shfl_xor(a, 16, 64);
        a += __shfl_xor(a, 8, 64);  a += __shfl_xor(a, 4, 64);
        a += __shfl_xor(a, 2, 64);  a += __shfl_xor(a, 1, 64);
        if (lane == 0) ws[WS_TW + l * B + b] = 1.f / (1.f + expf(-(a + Wb[it])));
    }
}

/* ---- table GEMM via MFMA: tab[b][n] = (U[b].G[n], P[b].G[n]) ----
   X[256][64] fp16 (rows 0-127 = utter, 128-255 = portrait); G fp16 hi + lo*4096
   residual (G effectively exact). 238 blocks x 128 nodes, 4 waves, M-tiles paired
   (b, b+128) so each lane writes float2(u,p) directly. */
__global__ __launch_bounds__(256) void k_table(
    const float* __restrict__ graph, const float* __restrict__ abs_e,
    const float* __restrict__ utter, float* __restrict__ ws) {
    __shared__ half_t Gs[128 * STRG];   /* 34.8 KB */
    __shared__ half_t Xs[256 * STRX];   /* 36.9 KB */
    const int nb = blockIdx.x, t = threadIdx.x;
    const float* port = ws + WS_PORT;

    /* stage G: 128 rows, hi|lo halves; 16 floats per (row,q) thread */
#pragma unroll
    for (int pz = 0; pz < 2; ++pz) {
        int row = pz * 64 + (t >> 2), q = t & 3;
        int n = nb * 128 + row;
        const float* src = ((n < N_NODES) ? (graph + (size_t)n * D) : abs_e) + q * 16;
        half_t* dh = &Gs[row * STRG + q * 16];
        half_t* dl = dh + 64;
        float4 f0 = *(const float4*)(src);
        float4 f1 = *(const float4*)(src + 4);
        float4 f2 = *(const float4*)(src + 8);
        float4 f3 = *(const float4*)(src + 12);
        half8 hh, ll;
        hh[0]=(half_t)f0.x; hh[1]=(half_t)f0.y; hh[2]=(half_t)f0.z; hh[3]=(half_t)f0.w;
        hh[4]=(half_t)f1.x; hh[5]=(half_t)f1.y; hh[6]=(half_t)f1.z; hh[7]=(half_t)f1.w;
        ll[0]=(half_t)((f0.x-(float)hh[0])*4096.f); ll[1]=(half_t)((f0.y-(float)hh[1])*4096.f);
        ll[2]=(half_t)((f0.z-(float)hh[2])*4096.f); ll[3]=(half_t)((f0.w-(float)hh[3])*4096.f);
        ll[4]=(half_t)((f1.x-(float)hh[4])*4096.f); ll[5]=(half_t)((f1.y-(float)hh[5])*4096.f);
        ll[6]=(half_t)((f1.z-(float)hh[6])*4096.f); ll[7]=(half_t)((f1.w-(float)hh[7])*4096.f);
        *(half8*)(dh) = hh; *(half8*)(dl) = ll;
        hh[0]=(half_t)f2.x; hh[1]=(half_t)f2.y; hh[2]=(half_t)f2.z; hh[3]=(half_t)f2.w;
        hh[4]=(half_t)f3.x; hh[5]=(half_t)f3.y; hh[6]=(half_t)f3.z; hh[7]=(half_t)f3.w;
        ll[0]=(half_t)((f2.x-(float)hh[0])*4096.f); ll[1]=(half_t)((f2.y-(float)hh[1])*4096.f);
        ll[2]=(half_t)((f2.z-(float)hh[2])*4096.f); ll[3]=(half_t)((f2.w-(float)hh[3])*4096.f);
        ll[4]=(half_t)((f3.x-(float)hh[4])*4096.f); ll[5]=(half_t)((f3.y-(float)hh[5])*4096.f);
        ll[6]=(half_t)((f3.z-(float)hh[6])*4096.f); ll[7]=(half_t)((f3.w-(float)hh[7])*4096.f);
        *(half8*)(dh + 8) = hh; *(half8*)(dl + 8) = ll;
    }
    /* stage X: rows 0-127 utter, 128-255 portrait; 32 floats per (row,c) thread,
       4 x half8 covering all of dx[0..32)  (round-3 bug: only 16 were written) */
#pragma unroll
    for (int pz = 0; pz < 2; ++pz) {
        int row = pz * 128 + (t >> 1), c = t & 1;
        const float* src = ((row < 128) ? (utter + (size_t)row * D)
                                        : (port + (size_t)(row - 128) * D)) + c * 32;
        half_t* dx = &Xs[row * STRX + c * 32];
#pragma unroll
        for (int g = 0; g < 4; ++g) {
            float4 f0 = *(const float4*)(src + g * 8);
            float4 f1 = *(const float4*)(src + g * 8 + 4);
            half8 hh;
            hh[0]=(half_t)f0.x; hh[1]=(half_t)f0.y; hh[2]=(half_t)f0.z; hh[3]=(half_t)f0.w;
            hh[4]=(half_t)f1.x; hh[5]=(half_t)f1.y; hh[6]=(half_t)f1.z; hh[7]=(half_t)f1.w;
            *(half8*)(dx + g * 8) = hh;
        }
    }
    __syncthreads();

    const int wv = t >> 6, m16 = t & 15, kq = (t & 63) >> 4;
    float2* tab = (float2*)(ws + WS_TAB);
    const f32x4 zero = {0.f, 0.f, 0.f, 0.f};

#pragma unroll
    for (int pp = 0; pp < 2; ++pp) {
        int pi = wv * 2 + pp;
        int ru = pi * 16 + m16, rp = 128 + pi * 16 + m16;
        half8 au0 = *(half8*)&Xs[ru * STRX + kq * 8];
        half8 au1 = *(half8*)&Xs[ru * STRX + 32 + kq * 8];
        half8 ap0 = *(half8*)&Xs[rp * STRX + kq * 8];
        half8 ap1 = *(half8*)&Xs[rp * STRX + 32 + kq * 8];
#pragma unroll
        for (int nt = 0; nt < 8; ++nt) {
            int n16 = nt * 16 + m16;
            const half_t* gr = &Gs[n16 * STRG + kq * 8];
            half8 bh0 = *(half8*)(gr);
            half8 bh1 = *(half8*)(gr + 32);
            half8 bl0 = *(half8*)(gr + 64);
            half8 bl1 = *(half8*)(gr + 96);
            f32x4 aU = zero, aUl = zero, aP = zero, aPl = zero;
            aU  = __builtin_amdgcn_mfma_f32_16x16x32_f16(au0, bh0, aU, 0, 0, 0);
            aU  = __builtin_amdgcn_mfma_f32_16x16x32_f16(au1, bh1, aU, 0, 0, 0);
            aUl = __builtin_amdgcn_mfma_f32_16x16x32_f16(au0, bl0, aUl, 0, 0, 0);
            aUl = __builtin_amdgcn_mfma_f32_16x16x32_f16(au1, bl1, aUl, 0, 0, 0);
            aP  = __builtin_amdgcn_mfma_f32_16x16x32_f16(ap0, bh0, aP, 0, 0, 0);
            aP  = __builtin_amdgcn_mfma_f32_16x16x32_f16(ap1, bh1, aP, 0, 0, 0);
            aPl = __builtin_amdgcn_mfma_f32_16x16x32_f16(ap0, bl0, aPl, 0, 0, 0);
            aPl = __builtin_amdgcn_mfma_f32_16x16x32_f16(ap1, bl1, aPl, 0, 0, 0);
            int n = nb * 128 + n16;
#pragma unroll
            for (int r = 0; r < 4; ++r) {
                int b = pi * 16 + kq * 4 + r;
                float u  = aU[r] + aUl[r] * 2.44140625e-4f;
                float pv = aP[r] + aPl[r] * 2.44140625e-4f;
                tab[(size_t)b * NPAD + n] = make_float2(u, pv);
            }
        }
    }
}

/* ---- scoring: one 8B gather + lerp per output; 2 outputs/thread ---- */
__global__ __launch_bounds__(256) void k_out(
    const int* __restrict__ si0, const int* __restrict__ si1,
    const float* __restrict__ ws, float* __restrict__ out) {
    const int l = blockIdx.y;
    const int* __restrict__ si = l ? si1 : si0;
    const float2* __restrict__ tab = (const float2*)(ws + WS_TAB);
    int s0 = (blockIdx.x * 256 + threadIdx.x) * 2;     /* K_SEL even -> same batch */
    int2 id = *(const int2*)(si + s0);
    unsigned bat = (unsigned)s0 / (unsigned)K_SEL;
    float tw = ws[WS_TW + l * B + bat];
    float2 v0 = tab[(size_t)bat * NPAD + id.x];
    float2 v1 = tab[(size_t)bat * NPAD + id.y];
    f32x2 r;
    r.x = v0.y + tw * (v0.x - v0.y);
    r.y = v1.y + tw * (v1.x - v1.y);
    __builtin_nontemporal_store(r, (f32x2*)&out[(size_t)l * S_TOT + s0]);
}

extern "C" void kernel_launch(void* const* d_in, const int* in_sizes, int n_in,
                              void* d_out, int out_size, void* d_ws, size_t ws_size,
                              hipStream_t stream) {
    const float* graph = (const float*)d_in[0];
    const float* utter = (const float*)d_in[1];
    const float* abs_e = (const float*)d_in[2];
    const float* Wa    = (const float*)d_in[3];
    const float* Va    = (const float*)d_in[4];
    const float* W1w   = (const float*)d_in[5];
    const float* W1b   = (const float*)d_in[6];
    const float* W2w   = (const float*)d_in[7];
    const float* W2b   = (const float*)d_in[8];
    const int* midx = (const int*)d_in[9];
    const int* si0 = (const int*)d_in[11];
    const int* la0 = (const int*)d_in[15];
    const int* it0 = (const int*)d_in[16];
    const int* si1 = (const int*)d_in[17];
    const int* la1 = (const int*)d_in[21];
    const int* it1 = (const int*)d_in[22];

    float* ws = (float*)d_ws;

    k_port<<<32, 256, 0, stream>>>(graph, abs_e, utter, Wa, Va,
                                   W1w, W1b, W2w, W2b, midx,
                                   la0, it0, la1, it1, ws);

    k_table<<<NB_CHUNKS, 256, 0, stream>>>(graph, abs_e, utter, ws);

    dim3 grid(S_TOT / 512, 2);   /* 1731 x 2 */
    k_out<<<grid, 256, 0, stream>>>(si0, si1, ws, (float*)d_out);
}

// Round 6
// 137.041 us; speedup vs baseline: 1.5560x; 1.1440x over previous
//
#include <hip/hip_runtime.h>
#include <cmath>

#define N_NODES 30460
#define D 64
#define B 128
#define K_SEL 6924
#define S_TOT (B * K_SEL)      /* 886272 */
#define NPAD 30464             /* 238*128 ; rows >= N_NODES hold abstract row */
#define NB_CHUNKS 238
#define NWG_OUT 3462           /* S_TOT/512 * 2 layers ; = 8*432 + 6 */

/* ws layout (float offsets): port [B*D] | tw [2*B] | tab half2 [B*NPAD] (~15.6 MB) */
#define WS_PORT 0
#define WS_TW   (B * D)
#define WS_TAB  (B * D + 2 * B)

typedef _Float16 half_t;
typedef _Float16 half8 __attribute__((ext_vector_type(8)));
typedef _Float16 half2_t __attribute__((ext_vector_type(2)));
typedef float f32x4 __attribute__((ext_vector_type(4)));
typedef float f32x2 __attribute__((ext_vector_type(2)));

#define STRG 72    /* Gs stride in halves: 64 + 8 pad ; 144 B, 16-aligned */
#define STRX 72    /* Xs stride in halves: 64 + 8 pad ; 144 B, 16-aligned */

/* ---- portrait + tw: 4 waves/block x 32 blocks = 128 batches (proven structure) ---- */
__global__ __launch_bounds__(256) void k_port(
    const float* __restrict__ graph, const float* __restrict__ abs_e,
    const float* __restrict__ utter,
    const float* __restrict__ Wa, const float* __restrict__ Va,
    const float* __restrict__ W1w, const float* __restrict__ W1b,
    const float* __restrict__ W2w, const float* __restrict__ W2b,
    const int* __restrict__ midx,
    const int* __restrict__ la0, const int* __restrict__ it0,
    const int* __restrict__ la1, const int* __restrict__ it1,
    float* __restrict__ ws) {
    __shared__ float sWa[D * 24];     /* padded stride 24 -> 16B-aligned float4 rows */
    __shared__ float sVa[20];
    __shared__ float sExp[4][64];
    __shared__ int   sIdx[4][64];
    int t = threadIdx.x, wave = t >> 6, lane = t & 63;
    for (int i = t; i < D * 20; i += 256) {
        int d = i / 20, j = i - d * 20;
        sWa[d * 24 + j] = Wa[i];
    }
    if (t < 20) sVa[t] = Va[t];
    __syncthreads();

    int b = blockIdx.x * 4 + wave;
    float e = 0.f; int mi = 0;
    if (lane < 50) {
        mi = midx[b * 50 + lane];
        const float* me = graph + (size_t)mi * D;
        float h[20];
#pragma unroll
        for (int j = 0; j < 20; j++) h[j] = 0.f;
#pragma unroll 2
        for (int d4 = 0; d4 < 16; ++d4) {
            float4 v = *(const float4*)(me + d4 * 4);
            const float* wb = &sWa[(d4 * 4) * 24];
#pragma unroll
            for (int e2 = 0; e2 < 4; ++e2) {
                float vv = (e2 == 0) ? v.x : (e2 == 1) ? v.y : (e2 == 2) ? v.z : v.w;
                const float* wr = wb + e2 * 24;
#pragma unroll
                for (int j4 = 0; j4 < 5; ++j4) {
                    float4 w = *(const float4*)(wr + j4 * 4);
                    h[j4 * 4 + 0] += vv * w.x;
                    h[j4 * 4 + 1] += vv * w.y;
                    h[j4 * 4 + 2] += vv * w.z;
                    h[j4 * 4 + 3] += vv * w.w;
                }
            }
        }
        float beta = 0.f;
#pragma unroll
        for (int j = 0; j < 20; j++) beta += tanhf(h[j]) * sVa[j];
        e = expf(beta);
    }
    sExp[wave][lane] = e;
    sIdx[wave][lane] = mi;
    __syncthreads();

    float x = e;
    x += __shfl_xor(x, 32, 64); x += __shfl_xor(x, 16, 64);
    x += __shfl_xor(x, 8, 64);  x += __shfl_xor(x, 4, 64);
    x += __shfl_xor(x, 2, 64);  x += __shfl_xor(x, 1, 64);

    float acc = 0.f;
#pragma unroll 10
    for (int m = 0; m < 50; m++)
        acc += sExp[wave][m] * graph[(size_t)sIdx[wave][m] * D + lane];
    float p = acc / x;
    ws[WS_PORT + b * D + lane] = p;
    float u = utter[(size_t)b * D + lane];

#pragma unroll
    for (int l = 0; l < 2; ++l) {
        const int* lap = l ? la1 : la0;
        const int* itp = l ? it1 : it0;
        const float* Ww = l ? W2w : W1w;
        const float* Wb = l ? W2b : W1b;
        int li = lap[b], it = itp[b];
        const float* wr = Ww + it * 3 * D;
        float sv = (li < N_NODES) ? graph[(size_t)li * D + lane] : abs_e[lane];
        float a = wr[lane] * u + wr[D + lane] * p + wr[2 * D + lane] * sv;
        a += __shfl_xor(a, 32, 64); a += __shfl_xor(a, 16, 64);
        a += __shfl_xor(a, 8, 64);  a += __shfl_xor(a, 4, 64);
        a += __shfl_xor(a, 2, 64);  a += __shfl_xor(a, 1, 64);
        if (lane == 0) ws[WS_TW + l * B + b] = 1.f / (1.f + expf(-(a + Wb[it])));
    }
}

/* ---- table GEMM via MFMA: tab[b][n] = half2(U[b].G[n], P[b].G[n]) ----
   X[256][64] fp16 (rows 0-127 = utter, 128-255 = portrait); G plain fp16
   (fp16 quantization ~1e-4 at 0.1-scale data; output floor is bf16 2^-10).
   238 blocks x 128 nodes, 4 waves; M-tiles paired (b, b+128) so each lane
   emits half2(u,p) directly. */
__global__ __launch_bounds__(256) void k_table(
    const float* __restrict__ graph, const float* __restrict__ abs_e,
    const float* __restrict__ utter, float* __restrict__ ws) {
    __shared__ half_t Gs[128 * STRG];   /* 18.4 KB */
    __shared__ half_t Xs[256 * STRX];   /* 36.9 KB */
    const int nb = blockIdx.x, t = threadIdx.x;
    const float* port = ws + WS_PORT;

    /* stage G: 128 rows; 16 floats per (row,q) thread */
#pragma unroll
    for (int pz = 0; pz < 2; ++pz) {
        int row = pz * 64 + (t >> 2), q = t & 3;
        int n = nb * 128 + row;
        const float* src = ((n < N_NODES) ? (graph + (size_t)n * D) : abs_e) + q * 16;
        half_t* dh = &Gs[row * STRG + q * 16];
        float4 f0 = *(const float4*)(src);
        float4 f1 = *(const float4*)(src + 4);
        float4 f2 = *(const float4*)(src + 8);
        float4 f3 = *(const float4*)(src + 12);
        half8 hh;
        hh[0]=(half_t)f0.x; hh[1]=(half_t)f0.y; hh[2]=(half_t)f0.z; hh[3]=(half_t)f0.w;
        hh[4]=(half_t)f1.x; hh[5]=(half_t)f1.y; hh[6]=(half_t)f1.z; hh[7]=(half_t)f1.w;
        *(half8*)(dh) = hh;
        hh[0]=(half_t)f2.x; hh[1]=(half_t)f2.y; hh[2]=(half_t)f2.z; hh[3]=(half_t)f2.w;
        hh[4]=(half_t)f3.x; hh[5]=(half_t)f3.y; hh[6]=(half_t)f3.z; hh[7]=(half_t)f3.w;
        *(half8*)(dh + 8) = hh;
    }
    /* stage X: rows 0-127 utter, 128-255 portrait; 32 floats per (row,c) thread */
#pragma unroll
    for (int pz = 0; pz < 2; ++pz) {
        int row = pz * 128 + (t >> 1), c = t & 1;
        const float* src = ((row < 128) ? (utter + (size_t)row * D)
                                        : (port + (size_t)(row - 128) * D)) + c * 32;
        half_t* dx = &Xs[row * STRX + c * 32];
#pragma unroll
        for (int g = 0; g < 4; ++g) {
            float4 f0 = *(const float4*)(src + g * 8);
            float4 f1 = *(const float4*)(src + g * 8 + 4);
            half8 hh;
            hh[0]=(half_t)f0.x; hh[1]=(half_t)f0.y; hh[2]=(half_t)f0.z; hh[3]=(half_t)f0.w;
            hh[4]=(half_t)f1.x; hh[5]=(half_t)f1.y; hh[6]=(half_t)f1.z; hh[7]=(half_t)f1.w;
            *(half8*)(dx + g * 8) = hh;
        }
    }
    __syncthreads();

    const int wv = t >> 6, m16 = t & 15, kq = (t & 63) >> 4;
    half2_t* tabh = (half2_t*)(ws + WS_TAB);
    const f32x4 zero = {0.f, 0.f, 0.f, 0.f};

#pragma unroll
    for (int pp = 0; pp < 2; ++pp) {
        int pi = wv * 2 + pp;
        int ru = pi * 16 + m16, rp = 128 + pi * 16 + m16;
        half8 au0 = *(half8*)&Xs[ru * STRX + kq * 8];
        half8 au1 = *(half8*)&Xs[ru * STRX + 32 + kq * 8];
        half8 ap0 = *(half8*)&Xs[rp * STRX + kq * 8];
        half8 ap1 = *(half8*)&Xs[rp * STRX + 32 + kq * 8];
#pragma unroll
        for (int nt = 0; nt < 8; ++nt) {
            int n16 = nt * 16 + m16;
            const half_t* gr = &Gs[n16 * STRG + kq * 8];
            half8 bh0 = *(half8*)(gr);
            half8 bh1 = *(half8*)(gr + 32);
            f32x4 aU = zero, aP = zero;
            aU = __builtin_amdgcn_mfma_f32_16x16x32_f16(au0, bh0, aU, 0, 0, 0);
            aU = __builtin_amdgcn_mfma_f32_16x16x32_f16(au1, bh1, aU, 0, 0, 0);
            aP = __builtin_amdgcn_mfma_f32_16x16x32_f16(ap0, bh0, aP, 0, 0, 0);
            aP = __builtin_amdgcn_mfma_f32_16x16x32_f16(ap1, bh1, aP, 0, 0, 0);
            int n = nb * 128 + n16;
#pragma unroll
            for (int r = 0; r < 4; ++r) {
                int b = pi * 16 + kq * 4 + r;
                half2_t hv;
                hv[0] = (half_t)aU[r];
                hv[1] = (half_t)aP[r];
                tabh[(size_t)b * NPAD + n] = hv;
            }
        }
    }
}

/* ---- scoring: one 4B gather + lerp per output; 2 outputs/thread ----
   XCD-swizzled (bijective, nwg=3462=8*432+6): each XCD owns a contiguous
   ~16-batch slice of s-space, BOTH layers -> per-XCD tab working set
   ~2 MB (half2), L2-resident. ---- */
__global__ __launch_bounds__(256) void k_out(
    const int* __restrict__ si0, const int* __restrict__ si1,
    const float* __restrict__ ws, float* __restrict__ out) {
    const int w = blockIdx.x;
    const int q = NWG_OUT / 8, r = NWG_OUT % 8;      /* 432, 6 */
    int xcd = w & 7, j = w >> 3;
    int work = (xcd < r ? xcd * (q + 1) : r * (q + 1) + (xcd - r) * q) + j;
    const int l = work & 1;
    const int x = work >> 1;                          /* 0..1730 */

    const int* __restrict__ si = l ? si1 : si0;
    const half2_t* __restrict__ tabh = (const half2_t*)(ws + WS_TAB);
    int s0 = (x * 256 + threadIdx.x) * 2;             /* K_SEL even -> same batch */
    int2 id = *(const int2*)(si + s0);
    unsigned bat = (unsigned)s0 / (unsigned)K_SEL;
    float tw = ws[WS_TW + l * B + bat];
    half2_t v0 = tabh[(size_t)bat * NPAD + id.x];
    half2_t v1 = tabh[(size_t)bat * NPAD + id.y];
    f32x2 rr;
    float u0 = (float)v0[0], p0 = (float)v0[1];
    float u1 = (float)v1[0], p1 = (float)v1[1];
    rr.x = p0 + tw * (u0 - p0);
    rr.y = p1 + tw * (u1 - p1);
    __builtin_nontemporal_store(rr, (f32x2*)&out[(size_t)l * S_TOT + s0]);
}

extern "C" void kernel_launch(void* const* d_in, const int* in_sizes, int n_in,
                              void* d_out, int out_size, void* d_ws, size_t ws_size,
                              hipStream_t stream) {
    const float* graph = (const float*)d_in[0];
    const float* utter = (const float*)d_in[1];
    const float* abs_e = (const float*)d_in[2];
    const float* Wa    = (const float*)d_in[3];
    const float* Va    = (const float*)d_in[4];
    const float* W1w   = (const float*)d_in[5];
    const float* W1b   = (const float*)d_in[6];
    const float* W2w   = (const float*)d_in[7];
    const float* W2b   = (const float*)d_in[8];
    const int* midx = (const int*)d_in[9];
    const int* si0 = (const int*)d_in[11];
    const int* la0 = (const int*)d_in[15];
    const int* it0 = (const int*)d_in[16];
    const int* si1 = (const int*)d_in[17];
    const int* la1 = (const int*)d_in[21];
    const int* it1 = (const int*)d_in[22];

    float* ws = (float*)d_ws;

    k_port<<<32, 256, 0, stream>>>(graph, abs_e, utter, Wa, Va,
                                   W1w, W1b, W2w, W2b, midx,
                                   la0, it0, la1, it1, ws);

    k_table<<<NB_CHUNKS, 256, 0, stream>>>(graph, abs_e, utter, ws);

    k_out<<<NWG_OUT, 256, 0, stream>>>(si0, si1, ws, (float*)d_out);
}

// Round 7
// 136.810 us; speedup vs baseline: 1.5586x; 1.0017x over previous
//
#include <hip/hip_runtime.h>
#include <cmath>

#define N_NODES 30460
#define D 64
#define B 128
#define K_SEL 6924
#define S_TOT (B * K_SEL)      /* 886272 */
#define NPAD 30464             /* 238*128 ; rows >= N_NODES hold abstract row */
#define NB_CHUNKS 238
#define NWG_OUT 3462           /* S_TOT/512 * 2 layers ; = 8*432 + 6 */

/* ws layout (float offsets):
   tw [2*B] | Xh half[256*64] (8192 floats) | tabL half[2*B*NPAD] (~15.6 MB) */
#define WS_TW  0
#define WS_XH  (2 * B)
#define WS_TAB (2 * B + (256 * D) / 2)

typedef _Float16 half_t;
typedef _Float16 half8 __attribute__((ext_vector_type(8)));
typedef float f32x4 __attribute__((ext_vector_type(4)));
typedef float f32x2 __attribute__((ext_vector_type(2)));

#define STRG 72    /* Gs stride in halves: 64 + 8 pad ; 144 B, 16-aligned */
#define STRX 72    /* Xs stride in halves: 64 + 8 pad ; 144 B, 16-aligned */

/* ---- portrait + tw + Xh: 4 waves/block x 32 blocks = 128 batches ----
   Emits: tw[2][B] fp32, Xh[256][64] fp16 (rows 0-127 utter, 128-255 portrait). */
__global__ __launch_bounds__(256) void k_port(
    const float* __restrict__ graph, const float* __restrict__ abs_e,
    const float* __restrict__ utter,
    const float* __restrict__ Wa, const float* __restrict__ Va,
    const float* __restrict__ W1w, const float* __restrict__ W1b,
    const float* __restrict__ W2w, const float* __restrict__ W2b,
    const int* __restrict__ midx,
    const int* __restrict__ la0, const int* __restrict__ it0,
    const int* __restrict__ la1, const int* __restrict__ it1,
    float* __restrict__ ws) {
    __shared__ float sWa[D * 24];     /* padded stride 24 -> 16B-aligned float4 rows */
    __shared__ float sVa[20];
    __shared__ float sExp[4][64];
    __shared__ int   sIdx[4][64];
    int t = threadIdx.x, wave = t >> 6, lane = t & 63;
    for (int i = t; i < D * 20; i += 256) {
        int d = i / 20, j = i - d * 20;
        sWa[d * 24 + j] = Wa[i];
    }
    if (t < 20) sVa[t] = Va[t];
    __syncthreads();

    int b = blockIdx.x * 4 + wave;
    float e = 0.f; int mi = 0;
    if (lane < 50) {
        mi = midx[b * 50 + lane];
        const float* me = graph + (size_t)mi * D;
        float h[20];
#pragma unroll
        for (int j = 0; j < 20; j++) h[j] = 0.f;
#pragma unroll 2
        for (int d4 = 0; d4 < 16; ++d4) {
            float4 v = *(const float4*)(me + d4 * 4);
            const float* wb = &sWa[(d4 * 4) * 24];
#pragma unroll
            for (int e2 = 0; e2 < 4; ++e2) {
                float vv = (e2 == 0) ? v.x : (e2 == 1) ? v.y : (e2 == 2) ? v.z : v.w;
                const float* wr = wb + e2 * 24;
#pragma unroll
                for (int j4 = 0; j4 < 5; ++j4) {
                    float4 w = *(const float4*)(wr + j4 * 4);
                    h[j4 * 4 + 0] += vv * w.x;
                    h[j4 * 4 + 1] += vv * w.y;
                    h[j4 * 4 + 2] += vv * w.z;
                    h[j4 * 4 + 3] += vv * w.w;
                }
            }
        }
        float beta = 0.f;
#pragma unroll
        for (int j = 0; j < 20; j++) beta += tanhf(h[j]) * sVa[j];
        e = expf(beta);
    }
    sExp[wave][lane] = e;
    sIdx[wave][lane] = mi;
    __syncthreads();

    float x = e;
    x += __shfl_xor(x, 32, 64); x += __shfl_xor(x, 16, 64);
    x += __shfl_xor(x, 8, 64);  x += __shfl_xor(x, 4, 64);
    x += __shfl_xor(x, 2, 64);  x += __shfl_xor(x, 1, 64);

    float acc = 0.f;
#pragma unroll 10
    for (int m = 0; m < 50; m++)
        acc += sExp[wave][m] * graph[(size_t)sIdx[wave][m] * D + lane];
    float p = acc / x;
    float u = utter[(size_t)b * D + lane];

    /* X rows as fp16: row b = utter, row 128+b = portrait */
    half_t* Xh = (half_t*)(ws + WS_XH);
    Xh[(size_t)b * D + lane] = (half_t)u;
    Xh[(size_t)(128 + b) * D + lane] = (half_t)p;

#pragma unroll
    for (int l = 0; l < 2; ++l) {
        const int* lap = l ? la1 : la0;
        const int* itp = l ? it1 : it0;
        const float* Ww = l ? W2w : W1w;
        const float* Wb = l ? W2b : W1b;
        int li = lap[b], it = itp[b];
        const float* wr = Ww + it * 3 * D;
        float sv = (li < N_NODES) ? graph[(size_t)li * D + lane] : abs_e[lane];
        float a = wr[lane] * u + wr[D + lane] * p + wr[2 * D + lane] * sv;
        a += __shfl_xor(a, 32, 64); a += __shfl_xor(a, 16, 64);
        a += __shfl_xor(a, 8, 64);  a += __shfl_xor(a, 4, 64);
        a += __shfl_xor(a, 2, 64);  a += __shfl_xor(a, 1, 64);
        if (lane == 0) ws[WS_TW + l * B + b] = 1.f / (1.f + expf(-(a + Wb[it])));
    }
}

/* ---- table GEMM via MFMA, blend fused: tabL[l][b][n] = half(tw*u + (1-tw)*p) ----
   X fp16 read pre-converted from ws (Xh); G staged fp32->fp16 in LDS.
   238 blocks x 128 nodes, 4 waves; per-lane blend with tw staged in LDS. */
__global__ __launch_bounds__(256) void k_table(
    const float* __restrict__ graph, const float* __restrict__ abs_e,
    float* __restrict__ ws) {
    __shared__ half_t Gs[128 * STRG];   /* 18.4 KB */
    __shared__ half_t Xs[256 * STRX];   /* 36.9 KB */
    __shared__ float sTw[2 * B];        /* 1 KB */
    const int nb = blockIdx.x, t = threadIdx.x;

    /* stage G: 128 rows; 16 floats per (row,q) thread */
#pragma unroll
    for (int pz = 0; pz < 2; ++pz) {
        int row = pz * 64 + (t >> 2), q = t & 3;
        int n = nb * 128 + row;
        const float* src = ((n < N_NODES) ? (graph + (size_t)n * D) : abs_e) + q * 16;
        half_t* dh = &Gs[row * STRG + q * 16];
        float4 f0 = *(const float4*)(src);
        float4 f1 = *(const float4*)(src + 4);
        float4 f2 = *(const float4*)(src + 8);
        float4 f3 = *(const float4*)(src + 12);
        half8 hh;
        hh[0]=(half_t)f0.x; hh[1]=(half_t)f0.y; hh[2]=(half_t)f0.z; hh[3]=(half_t)f0.w;
        hh[4]=(half_t)f1.x; hh[5]=(half_t)f1.y; hh[6]=(half_t)f1.z; hh[7]=(half_t)f1.w;
        *(half8*)(dh) = hh;
        hh[0]=(half_t)f2.x; hh[1]=(half_t)f2.y; hh[2]=(half_t)f2.z; hh[3]=(half_t)f2.w;
        hh[4]=(half_t)f3.x; hh[5]=(half_t)f3.y; hh[6]=(half_t)f3.z; hh[7]=(half_t)f3.w;
        *(half8*)(dh + 8) = hh;
    }
    /* stage X: straight fp16 copy from Xh (256 rows x 64 halves) */
    {
        const half_t* Xh = (const half_t*)(ws + WS_XH);
#pragma unroll
        for (int pz = 0; pz < 8; ++pz) {
            int i = pz * 256 + t;           /* half8 chunk id: 2048 total */
            int row = i >> 3, c8 = i & 7;
            *(half8*)&Xs[row * STRX + c8 * 8] =
                *(const half8*)&Xh[(size_t)row * D + c8 * 8];
        }
    }
    /* stage tw */
    sTw[t] = ws[WS_TW + t] * 0.f + ws[WS_TW + (t & 255)];  /* t<256 == 2*B exactly */
    __syncthreads();

    const int wv = t >> 6, m16 = t & 15, kq = (t & 63) >> 4;
    half_t* tabL = (half_t*)(ws + WS_TAB);
    const f32x4 zero = {0.f, 0.f, 0.f, 0.f};

#pragma unroll
    for (int pp = 0; pp < 2; ++pp) {
        int pi = wv * 2 + pp;
        int ru = pi * 16 + m16, rp = 128 + pi * 16 + m16;
        half8 au0 = *(half8*)&Xs[ru * STRX + kq * 8];
        half8 au1 = *(half8*)&Xs[ru * STRX + 32 + kq * 8];
        half8 ap0 = *(half8*)&Xs[rp * STRX + kq * 8];
        half8 ap1 = *(half8*)&Xs[rp * STRX + 32 + kq * 8];
#pragma unroll
        for (int nt = 0; nt < 8; ++nt) {
            int n16 = nt * 16 + m16;
            const half_t* gr = &Gs[n16 * STRG + kq * 8];
            half8 bh0 = *(half8*)(gr);
            half8 bh1 = *(half8*)(gr + 32);
            f32x4 aU = zero, aP = zero;
            aU = __builtin_amdgcn_mfma_f32_16x16x32_f16(au0, bh0, aU, 0, 0, 0);
            aU = __builtin_amdgcn_mfma_f32_16x16x32_f16(au1, bh1, aU, 0, 0, 0);
            aP = __builtin_amdgcn_mfma_f32_16x16x32_f16(ap0, bh0, aP, 0, 0, 0);
            aP = __builtin_amdgcn_mfma_f32_16x16x32_f16(ap1, bh1, aP, 0, 0, 0);
            int n = nb * 128 + n16;
#pragma unroll
            for (int r = 0; r < 4; ++r) {
                int b = pi * 16 + kq * 4 + r;
                float u = aU[r], p = aP[r], d = u - p;
                tabL[(size_t)b * NPAD + n] = (half_t)(p + sTw[b] * d);
                tabL[(size_t)(B + b) * NPAD + n] = (half_t)(p + sTw[B + b] * d);
            }
        }
    }
}

/* ---- scoring: one 2B gather + cvt per output; 2 outputs/thread ----
   XCD-swizzled (bijective): each XCD owns contiguous work ids -> ~1 MB
   tabL slice, L2-resident. No tw, no lerp (blend fused into table). ---- */
__global__ __launch_bounds__(256) void k_out(
    const int* __restrict__ si0, const int* __restrict__ si1,
    const float* __restrict__ ws, float* __restrict__ out) {
    const int w = blockIdx.x;
    const int q = NWG_OUT / 8, r = NWG_OUT % 8;      /* 432, 6 */
    int xcd = w & 7, j = w >> 3;
    int work = (xcd < r ? xcd * (q + 1) : r * (q + 1) + (xcd - r) * q) + j;
    const int l = work & 1;
    const int x = work >> 1;                          /* 0..1730 */

    const int* __restrict__ si = l ? si1 : si0;
    const half_t* __restrict__ tabL =
        (const half_t*)(ws + WS_TAB) + (size_t)l * B * NPAD;
    int s0 = (x * 256 + threadIdx.x) * 2;             /* K_SEL even -> same batch */
    int2 id = *(const int2*)(si + s0);
    unsigned bat = (unsigned)s0 / (unsigned)K_SEL;
    const half_t* row = tabL + (size_t)bat * NPAD;
    half_t v0 = row[id.x];
    half_t v1 = row[id.y];
    f32x2 rr;
    rr.x = (float)v0;
    rr.y = (float)v1;
    __builtin_nontemporal_store(rr, (f32x2*)&out[(size_t)l * S_TOT + s0]);
}

extern "C" void kernel_launch(void* const* d_in, const int* in_sizes, int n_in,
                              void* d_out, int out_size, void* d_ws, size_t ws_size,
                              hipStream_t stream) {
    const float* graph = (const float*)d_in[0];
    const float* utter = (const float*)d_in[1];
    const float* abs_e = (const float*)d_in[2];
    const float* Wa    = (const float*)d_in[3];
    const float* Va    = (const float*)d_in[4];
    const float* W1w   = (const float*)d_in[5];
    const float* W1b   = (const float*)d_in[6];
    const float* W2w   = (const float*)d_in[7];
    const float* W2b   = (const float*)d_in[8];
    const int* midx = (const int*)d_in[9];
    const int* si0 = (const int*)d_in[11];
    const int* la0 = (const int*)d_in[15];
    const int* it0 = (const int*)d_in[16];
    const int* si1 = (const int*)d_in[17];
    const int* la1 = (const int*)d_in[21];
    const int* it1 = (const int*)d_in[22];

    float* ws = (float*)d_ws;

    k_port<<<32, 256, 0, stream>>>(graph, abs_e, utter, Wa, Va,
                                   W1w, W1b, W2w, W2b, midx,
                                   la0, it0, la1, it1, ws);

    k_table<<<NB_CHUNKS, 256, 0, stream>>>(graph, abs_e, ws);

    k_out<<<NWG_OUT, 256, 0, stream>>>(si0, si1, ws, (float*)d_out);
}